// Round 1
// baseline (30129.535 us; speedup 1.0000x reference)
//
#include <hip/hip_runtime.h>
#include <math.h>

#define B_ 32
#define S_ 100
#define T_ 100
#define E_ 512
#define H_ 1024
#define V_ 32000
#define G4 4096   /* 4*H */

// ---------------------------------------------------------------------------
// Generic tiled fp32 GEMM: C[M,N] = gatherA[M,K] @ W[K,N] + bias
// 128x128 tile, BK=16, 256 threads, 8x8 micro-tile. All dims are exact
// multiples (M=3200, N in {1024,4096,32000}, K in {512,1024}) -> no bounds.
// ---------------------------------------------------------------------------
__global__ __launch_bounds__(256) void gemm_bias(
    const float* __restrict__ A, const int* __restrict__ idx, int lda,
    const float* __restrict__ Bw, int ldb,
    const float* __restrict__ bias,
    float* __restrict__ C, int ldc, int K)
{
    __shared__ float As[16][132];
    __shared__ float Bs[16][132];
    const int tid = threadIdx.x;
    const int m0 = blockIdx.y * 128;
    const int n0 = blockIdx.x * 128;
    const int tx = tid & 15, ty = tid >> 4;

    int a_row = m0 + (tid & 127);
    if (idx) a_row = idx[a_row];
    const int a_k = (tid >> 7) << 3;                 // 0 or 8
    const float* Ap = A + (long)a_row * lda + a_k;
    const int b_k = tid >> 4;                        // 0..15
    const int b_n = (tid & 15) << 3;                 // 0..120
    const float* Bp = Bw + (long)b_k * ldb + n0 + b_n;

    float acc[8][8];
#pragma unroll
    for (int i = 0; i < 8; ++i)
#pragma unroll
        for (int j = 0; j < 8; ++j) acc[i][j] = 0.f;

    for (int k0 = 0; k0 < K; k0 += 16) {
        float4 av0 = *(const float4*)(Ap + k0);
        float4 av1 = *(const float4*)(Ap + k0 + 4);
        float4 bv0 = *(const float4*)(Bp + (long)k0 * ldb);
        float4 bv1 = *(const float4*)(Bp + (long)k0 * ldb + 4);
        __syncthreads();
        const int ar = tid & 127;
        As[a_k + 0][ar] = av0.x; As[a_k + 1][ar] = av0.y;
        As[a_k + 2][ar] = av0.z; As[a_k + 3][ar] = av0.w;
        As[a_k + 4][ar] = av1.x; As[a_k + 5][ar] = av1.y;
        As[a_k + 6][ar] = av1.z; As[a_k + 7][ar] = av1.w;
        *(float4*)&Bs[b_k][b_n]     = bv0;
        *(float4*)&Bs[b_k][b_n + 4] = bv1;
        __syncthreads();
#pragma unroll
        for (int k = 0; k < 16; ++k) {
            float4 a0 = *(const float4*)&As[k][ty << 3];
            float4 a1 = *(const float4*)&As[k][(ty << 3) + 4];
            float4 b0 = *(const float4*)&Bs[k][tx << 3];
            float4 b1 = *(const float4*)&Bs[k][(tx << 3) + 4];
            float aa[8] = {a0.x, a0.y, a0.z, a0.w, a1.x, a1.y, a1.z, a1.w};
            float bb[8] = {b0.x, b0.y, b0.z, b0.w, b1.x, b1.y, b1.z, b1.w};
#pragma unroll
            for (int i = 0; i < 8; ++i)
#pragma unroll
                for (int j = 0; j < 8; ++j) acc[i][j] += aa[i] * bb[j];
        }
    }

    float bb[8];
#pragma unroll
    for (int j = 0; j < 8; ++j) bb[j] = bias ? bias[n0 + (tx << 3) + j] : 0.f;
#pragma unroll
    for (int i = 0; i < 8; ++i) {
        float* Cp = C + (long)(m0 + (ty << 3) + i) * ldc + n0 + (tx << 3);
        float4 o0 = {acc[i][0] + bb[0], acc[i][1] + bb[1], acc[i][2] + bb[2], acc[i][3] + bb[3]};
        float4 o1 = {acc[i][4] + bb[4], acc[i][5] + bb[5], acc[i][6] + bb[6], acc[i][7] + bb[7]};
        *(float4*)Cp = o0;
        *(float4*)(Cp + 4) = o1;
    }
}

// ---------------------------------------------------------------------------
// Small-M recurrent GEMM, split-K partials:
//   part[slot][32][N] = A[32, k0:k0+Kc] @ W[k0:k0+Kc, :N]   (slot = z*gridDim.y + y)
// blockIdx.z selects (A0,W0) or (A1,W1). Grid: (N/256, P, nA). lda = H.
// Thread: 4 rows x 8 cols.
// ---------------------------------------------------------------------------
__global__ __launch_bounds__(256) void rec_partial(
    const float* __restrict__ A0, const float* __restrict__ A1,
    const float* __restrict__ W0, const float* __restrict__ W1, int ldw,
    float* __restrict__ part, int N, int Kc)
{
    const float* A = blockIdx.z ? A1 : A0;
    const float* W = blockIdx.z ? W1 : W0;
    const int slot = blockIdx.z * gridDim.y + blockIdx.y;
    const int k0 = blockIdx.y * Kc;
    const int n0 = blockIdx.x * 256;
    const int cg = threadIdx.x & 31, rg = threadIdx.x >> 5;
    const int c0 = n0 + (cg << 3);
    const int r0 = rg << 2;

    float acc[4][8];
#pragma unroll
    for (int r = 0; r < 4; ++r)
#pragma unroll
        for (int j = 0; j < 8; ++j) acc[r][j] = 0.f;

    for (int kk = 0; kk < Kc; kk += 8) {
        float a[4][8];
#pragma unroll
        for (int r = 0; r < 4; ++r) {
            const float* Ap = A + (long)(r0 + r) * H_ + k0 + kk;
            float4 v0 = *(const float4*)Ap;
            float4 v1 = *(const float4*)(Ap + 4);
            a[r][0] = v0.x; a[r][1] = v0.y; a[r][2] = v0.z; a[r][3] = v0.w;
            a[r][4] = v1.x; a[r][5] = v1.y; a[r][6] = v1.z; a[r][7] = v1.w;
        }
#pragma unroll
        for (int k = 0; k < 8; ++k) {
            const float* Wp = W + (long)(k0 + kk + k) * ldw + c0;
            float4 w0 = *(const float4*)Wp;
            float4 w1 = *(const float4*)(Wp + 4);
            float ww[8] = {w0.x, w0.y, w0.z, w0.w, w1.x, w1.y, w1.z, w1.w};
#pragma unroll
            for (int r = 0; r < 4; ++r)
#pragma unroll
                for (int j = 0; j < 8; ++j) acc[r][j] += a[r][k] * ww[j];
        }
    }

#pragma unroll
    for (int r = 0; r < 4; ++r) {
        float* Pp = part + ((long)slot * B_ + r0 + r) * N + c0;
        float4 o0 = {acc[r][0], acc[r][1], acc[r][2], acc[r][3]};
        float4 o1 = {acc[r][4], acc[r][5], acc[r][6], acc[r][7]};
        *(float4*)Pp = o0;
        *(float4*)(Pp + 4) = o1;
    }
}

// ---------------------------------------------------------------------------
// Sum split-K partials + precomputed xW row, apply LSTM cell (i,f,g,o order).
// 32768 threads (b = gid>>10, j = gid&1023).
// ---------------------------------------------------------------------------
__global__ __launch_bounds__(256) void lstm_combine(
    const float* __restrict__ xW, long xw_row_stride,
    const float* __restrict__ part, int n_slots,
    float* __restrict__ h, float* __restrict__ c,
    float* __restrict__ h_extra, long extra_row_stride)
{
    const int gid = blockIdx.x * 256 + threadIdx.x;
    const int b = gid >> 10, j = gid & (H_ - 1);
    float g4[4];
#pragma unroll
    for (int g = 0; g < 4; ++g) {
        const int n = g * H_ + j;
        float s = xW[(long)b * xw_row_stride + n];
        for (int p = 0; p < n_slots; ++p)
            s += part[((long)p * B_ + b) * G4 + n];
        g4[g] = s;
    }
    const float ii = 1.f / (1.f + expf(-g4[0]));
    const float ff = 1.f / (1.f + expf(-g4[1]));
    const float gg = tanhf(g4[2]);
    const float oo = 1.f / (1.f + expf(-g4[3]));
    const float cn = ff * c[gid] + ii * gg;
    const float hn = oo * tanhf(cn);
    c[gid] = cn;
    h[gid] = hn;
    if (h_extra) h_extra[(long)b * extra_row_stride + j] = hn;
}

// ---------------------------------------------------------------------------
// Attention: per-b block. scores = enc_proj[b] . h[b]; softmax; atten = w.enc_out
// ---------------------------------------------------------------------------
__global__ __launch_bounds__(256) void attention_k(
    const float* __restrict__ enc_proj, const float* __restrict__ enc_out,
    const float* __restrict__ h, float* __restrict__ atten)
{
    __shared__ float hb[H_];
    __shared__ float sc[128];
    const int b = blockIdx.x;
    const int tid = threadIdx.x;
    for (int i = tid; i < H_; i += 256) hb[i] = h[b * H_ + i];
    __syncthreads();

    const int wave = tid >> 6, lane = tid & 63;
    for (int s = wave; s < S_; s += 4) {
        const float* pr = enc_proj + ((long)b * S_ + s) * H_;
        float acc = 0.f;
        for (int k = lane; k < H_; k += 64) acc += pr[k] * hb[k];
#pragma unroll
        for (int off = 32; off; off >>= 1) acc += __shfl_xor(acc, off);
        if (lane == 0) sc[s] = acc;
    }
    __syncthreads();

    if (tid < 64) {
        float v0 = (tid < S_) ? sc[tid] : -1e30f;
        float v1 = (tid + 64 < S_) ? sc[tid + 64] : -1e30f;
        float mx = fmaxf(v0, v1);
#pragma unroll
        for (int off = 32; off; off >>= 1) mx = fmaxf(mx, __shfl_xor(mx, off));
        float e0 = (tid < S_) ? expf(v0 - mx) : 0.f;
        float e1 = (tid + 64 < S_) ? expf(v1 - mx) : 0.f;
        float ss = e0 + e1;
#pragma unroll
        for (int off = 32; off; off >>= 1) ss += __shfl_xor(ss, off);
        const float inv = 1.f / ss;
        if (tid < S_) sc[tid] = e0 * inv;
        if (tid + 64 < S_) sc[tid + 64] = e1 * inv;
    }
    __syncthreads();

    for (int k = tid; k < H_; k += 256) {
        float acc = 0.f;
        for (int s = 0; s < S_; ++s)
            acc += sc[s] * enc_out[((long)b * S_ + s) * H_ + k];
        atten[b * H_ + k] = acc;
    }
}

// ---------------------------------------------------------------------------
// feed = tanh(sum partials + bias); also store into hidden_all[:, t, :]
// ---------------------------------------------------------------------------
__global__ __launch_bounds__(256) void feed_combine(
    const float* __restrict__ part, int n_slots, const float* __restrict__ bias,
    float* __restrict__ feed, float* __restrict__ hidden_t, long hid_row_stride)
{
    const int gid = blockIdx.x * 256 + threadIdx.x;
    const int b = gid >> 10, j = gid & (H_ - 1);
    float s = bias[j];
    for (int p = 0; p < n_slots; ++p)
        s += part[((long)p * B_ + b) * H_ + j];
    const float v = tanhf(s);
    feed[gid] = v;
    hidden_t[(long)b * hid_row_stride + j] = v;
}

__global__ void init_hc(float* h, float* c)
{
    const int i = blockIdx.x * 256 + threadIdx.x;
    h[i] = 0.f;
    c[i] = 0.f;
}

__global__ void copy_vec(const float* __restrict__ s, float* __restrict__ d)
{
    const int i = blockIdx.x * 256 + threadIdx.x;
    d[i] = s[i];
}

// ---------------------------------------------------------------------------
extern "C" void kernel_launch(void* const* d_in, const int* in_sizes, int n_in,
                              void* d_out, int out_size, void* d_ws, size_t ws_size,
                              hipStream_t stream)
{
    const int*   src_idx  = (const int*)  d_in[0];
    const int*   tgt_idx  = (const int*)  d_in[1];
    const float* src_emb  = (const float*)d_in[2];
    const float* tgt_emb  = (const float*)d_in[3];
    const float* enc_Wih  = (const float*)d_in[4];
    const float* enc_Whh  = (const float*)d_in[5];
    const float* enc_b    = (const float*)d_in[6];
    const float* dec_Wih  = (const float*)d_in[7];
    const float* dec_Whh  = (const float*)d_in[8];
    const float* dec_b    = (const float*)d_in[9];
    const float* att1_W   = (const float*)d_in[10];
    const float* att1_b   = (const float*)d_in[11];
    const float* cls1_W   = (const float*)d_in[12];
    const float* cls1_b   = (const float*)d_in[13];
    const float* cls2_W   = (const float*)d_in[14];
    const float* cls2_b   = (const float*)d_in[15];
    float* out = (float*)d_out;

    float* ws = (float*)d_ws;
    float* xW       = ws;                         // 3200*4096  (enc, then dec)
    float* enc_out  = xW       + (long)3200 * G4; // 3200*1024
    float* enc_proj = enc_out  + (long)3200 * H_; // 3200*1024
    float* hidden   = enc_proj + (long)3200 * H_; // 3200*1024
    float* h        = hidden   + (long)3200 * H_; // 32*1024
    float* c        = h        + B_ * H_;
    float* feed     = c        + B_ * H_;
    float* atten    = feed     + B_ * H_;
    float* partG    = atten    + B_ * H_;         // 32 * 32*4096
    float* partC    = partG    + (long)32 * B_ * G4; // 64 * 32*1024

    // 1) enc_xW = src_emb[src] @ enc_Wih + enc_b   -> xW [B,S,4H] row b*S+s
    gemm_bias<<<dim3(G4 / 128, 3200 / 128), 256, 0, stream>>>(
        src_emb, src_idx, E_, enc_Wih, G4, enc_b, xW, G4, E_);

    // 2) h = c = 0
    init_hc<<<B_ * H_ / 256, 256, 0, stream>>>(h, c);

    // 3) encoder
    for (int t = 0; t < S_; ++t) {
        rec_partial<<<dim3(G4 / 256, 16, 1), 256, 0, stream>>>(
            h, h, enc_Whh, enc_Whh, G4, partG, G4, H_ / 16);
        lstm_combine<<<B_ * H_ / 256, 256, 0, stream>>>(
            xW + (long)t * G4, (long)S_ * G4, partG, 16, h, c,
            enc_out + (long)t * H_, (long)S_ * H_);
    }

    // 4) enc_proj = enc_out @ att1_W + att1_b
    gemm_bias<<<dim3(H_ / 128, 3200 / 128), 256, 0, stream>>>(
        enc_out, (const int*)nullptr, H_, att1_W, H_, att1_b, enc_proj, H_, H_);

    // 5) dec_xW = tgt_emb[tgt] @ dec_Wih[0:E] + dec_b   -> xW [B,T,4H] row b*T+t
    gemm_bias<<<dim3(G4 / 128, 3200 / 128), 256, 0, stream>>>(
        tgt_emb, tgt_idx, E_, dec_Wih, G4, dec_b, xW, G4, E_);

    // 6) feed = h (enc final hidden)
    copy_vec<<<B_ * H_ / 256, 256, 0, stream>>>(h, feed);

    // 7) decoder
    for (int t = 0; t < T_; ++t) {
        // gates partials: feed @ dec_Wih[E:E+H] and h @ dec_Whh
        rec_partial<<<dim3(G4 / 256, 16, 2), 256, 0, stream>>>(
            feed, h, dec_Wih + (long)E_ * G4, dec_Whh, G4, partG, G4, H_ / 16);
        lstm_combine<<<B_ * H_ / 256, 256, 0, stream>>>(
            xW + (long)t * G4, (long)T_ * G4, partG, 32, h, c,
            (float*)nullptr, 0);
        attention_k<<<B_, 256, 0, stream>>>(enc_proj, enc_out, h, atten);
        // feed partials: atten @ cls1_W[0:H] and h @ cls1_W[H:2H]
        rec_partial<<<dim3(H_ / 256, 32, 2), 256, 0, stream>>>(
            atten, h, cls1_W, cls1_W + (long)H_ * H_, H_, partC, H_, H_ / 32);
        feed_combine<<<B_ * H_ / 256, 256, 0, stream>>>(
            partC, 64, cls1_b, feed, hidden + (long)t * H_, (long)T_ * H_);
    }

    // 8) out = hidden @ cls2_W + cls2_b   [3200, 32000]
    gemm_bias<<<dim3(V_ / 128, 3200 / 128), 256, 0, stream>>>(
        hidden, (const int*)nullptr, H_, cls2_W, V_, cls2_b, out, V_, H_);
}